// Round 3
// baseline (29029.196 us; speedup 1.0000x reference)
//
#include <hip/hip_runtime.h>

// 2-layer tanh RNN, B=64, S=2048, D=HID=512.
// Round 10: self-validating XCD-local transport.
// Geometry (as r8/r9): block = 128 thr = wave0 (L0,jg) + wave1 (L1,jg);
// blockIdx = jg*8 + bg, residues 4..7 exit => the 64 waves of a batch-group
// share one XCD (XCD = blockIdx % 8 round-robin, m157-validated).
//
// r9 post-mortem: ran to completion with garbage => placement check PASSED,
// but sc0 loads still hit stale per-CU L1 (flag line pinned hot -> polls
// never advance -> sticky degrade -> bounded wrong answer). ISA argument:
// no L1-writeback instruction exists => L1 is write-through => producer
// stores DID reach L2; the consumer side was broken.
//
// Fast path, zero inline asm:
//   reads  = relaxed workgroup-scope atomic fetch_add(p,0): global atomics
//            execute at the TCC (L2) and never hit vector L1.
//   writes = plain/workgroup atomic stores (write-through L1) + vmcnt(0)
//            drain before the flag stamp.
// Self-validation: steps 0..7 compute on the round-7 agent-scope protocol
// (ground truth) while mirroring through the fast protocol and bit-comparing
// (h data + flag visibility). Any defect ORs into verdict[bg]; step 8 then
// adopts fast (verdict 0) or stays slow + a 2 ms telemetry stall (verdict 1).
// Outcomes: ~3-4.5 ms PASS = fast works; ~18 ms PASS = premise falsified.

#define SEQ   2048
#define PROBE 8

typedef _Float16 half8 __attribute__((ext_vector_type(8)));
typedef float floatx4 __attribute__((ext_vector_type(4)));
typedef unsigned long long u64;

__device__ inline half8 cvt8(const float* p) {
    float4 f0 = ((const float4*)p)[0];
    float4 f1 = ((const float4*)p)[1];
    half8 h;
    h[0]=(_Float16)f0.x; h[1]=(_Float16)f0.y; h[2]=(_Float16)f0.z; h[3]=(_Float16)f0.w;
    h[4]=(_Float16)f1.x; h[5]=(_Float16)f1.y; h[6]=(_Float16)f1.z; h[7]=(_Float16)f1.w;
    return h;
}

// ===== agent-scope (MALL) primitives — round-7 proven slow path =====
__device__ inline u64 ld8_l3(const void* p) {
    return __hip_atomic_load((const u64*)p, __ATOMIC_RELAXED, __HIP_MEMORY_SCOPE_AGENT);
}
__device__ inline half8 ldfrag_l3(const _Float16* p) {
    union { u64 d[2]; half8 h; } u;
    u.d[0] = ld8_l3(p); u.d[1] = ld8_l3(p + 4);
    return u.h;
}
__device__ inline int ldflag_l3(const int* p) {
    return __hip_atomic_load(p, __ATOMIC_RELAXED, __HIP_MEMORY_SCOPE_AGENT);
}
__device__ inline void st2_l3(_Float16* p, unsigned short v) {
    __hip_atomic_store((unsigned short*)p, v, __ATOMIC_RELAXED, __HIP_MEMORY_SCOPE_AGENT);
}
__device__ inline void stflag_l3(int* p, int v) {
    __hip_atomic_store(p, v, __ATOMIC_RELAXED, __HIP_MEMORY_SCOPE_AGENT);
}

// ===== XCD-local (TCC/L2) primitives — fast path =====
__device__ inline u64 rmw8(_Float16* p) {           // L1-bypassing 8B read
    return __hip_atomic_fetch_add((u64*)(void*)p, 0ull, __ATOMIC_RELAXED,
                                  __HIP_MEMORY_SCOPE_WORKGROUP);
}
__device__ inline half8 ldfrag_l2(_Float16* p) {
    union { u64 d[2]; half8 h; } u;
    u.d[0] = rmw8(p); u.d[1] = rmw8(p + 4);
    return u.h;
}
__device__ inline int ldflag_l2(int* p) {           // L1-bypassing flag read
    return __hip_atomic_fetch_add(p, 0, __ATOMIC_RELAXED,
                                  __HIP_MEMORY_SCOPE_WORKGROUP);
}
__device__ inline void st2_l2(_Float16* p, unsigned short v) {
    __hip_atomic_store((unsigned short*)p, v, __ATOMIC_RELAXED,
                       __HIP_MEMORY_SCOPE_WORKGROUP);
}
__device__ inline void stflag_l2(int* p, int v) {
    __hip_atomic_store(p, v, __ATOMIC_RELAXED, __HIP_MEMORY_SCOPE_WORKGROUP);
}

__device__ inline int neq8(half8 a, half8 b) {
    union { half8 h; u64 d[2]; } ua, ub; ua.h = a; ub.h = b;
    return (ua.d[0] != ub.d[0]) | (ua.d[1] != ub.d[1]);
}

#define MFMA(a, b, c) __builtin_amdgcn_mfma_f32_16x16x32_f16((a), (b), (c), 0, 0, 0)

// ===== main loop, M = 0 slow (agent) / 1 fast (XCD-L2) =====
template<int M>
__device__ __forceinline__ void run_range(
    const int t0, const int lane, const int L, const int bg, const int jg,
    const int* __restrict__ src, const float* __restrict__ embed,
    const half8* bw, const float bias, float* __restrict__ out,
    _Float16* h0s, _Float16* h1s, int* flg)
{
    const int q    = lane >> 4;
    const int rr   = lane & 15;
    const int col  = jg * 16 + rr;
    const int arow = bg * 16 + rr;
    const int lf   = lane >> 5;
    int degraded = 0;      // sticky: first fast-poll timeout shrinks bounds

    for (int t = t0; t < SEQ; ++t) {
        floatx4 acc0 = {0.f,0.f,0.f,0.f}, acc1 = {0.f,0.f,0.f,0.f};

        if (L == 0) {
            const int erow = src[arow * SEQ + t];
            const float* eb = embed + (size_t)erow * 512 + q * 8;
            half8 ax[16];
            #pragma unroll
            for (int u = 0; u < 16; ++u) ax[u] = cvt8(eb + u * 32);
            #pragma unroll
            for (int u = 0; u < 16; ++u) {
                if (u & 1) acc1 = MFMA(ax[u], bw[u], acc1);
                else       acc0 = MFMA(ax[u], bw[u], acc0);
            }
            const int tgt = (lf == 0) ? t : (t - 3);
            {
                const long bound = (M == 0) ? (1L << 26)
                                            : (degraded ? 64 : (1L << 16));
                bool ok = false;
                for (long it = 0; it < bound; ++it) {
                    int v = (M == 0) ? ldflag_l3(&flg[lane]) : ldflag_l2(&flg[lane]);
                    if (__ballot(v >= tgt) == ~0ull) { ok = true; break; }
                    __builtin_amdgcn_s_sleep(1);
                }
                if (!ok) degraded = 1;
            }
            __atomic_signal_fence(__ATOMIC_SEQ_CST);
            if (t > 0) {
                _Float16* hb = h0s + ((t - 1) & 3) * (64 * 512) + arow * 512 + q * 8;
                half8 ah[16];
                #pragma unroll
                for (int u = 0; u < 16; ++u)
                    ah[u] = (M == 0) ? ldfrag_l3(hb + u * 32) : ldfrag_l2(hb + u * 32);
                #pragma unroll
                for (int u = 0; u < 16; ++u) {
                    if (u & 1) acc1 = MFMA(ah[u], bw[16 + u], acc1);
                    else       acc0 = MFMA(ah[u], bw[16 + u], acc0);
                }
            }
        } else {
            const int tgt = (lf == 0) ? (t + 1) : t;
            {
                const long bound = (M == 0) ? (1L << 26)
                                            : (degraded ? 64 : (1L << 16));
                bool ok = false;
                for (long it = 0; it < bound; ++it) {
                    int v = (M == 0) ? ldflag_l3(&flg[lane]) : ldflag_l2(&flg[lane]);
                    if (__ballot(v >= tgt) == ~0ull) { ok = true; break; }
                    __builtin_amdgcn_s_sleep(1);
                }
                if (!ok) degraded = 1;
            }
            __atomic_signal_fence(__ATOMIC_SEQ_CST);
            {
                _Float16* xa = h0s + (t & 3) * (64 * 512) + arow * 512 + q * 8;
                half8 ax[16];
                #pragma unroll
                for (int u = 0; u < 16; ++u)
                    ax[u] = (M == 0) ? ldfrag_l3(xa + u * 32) : ldfrag_l2(xa + u * 32);
                #pragma unroll
                for (int u = 0; u < 16; ++u) {
                    if (u & 1) acc1 = MFMA(ax[u], bw[u], acc1);
                    else       acc0 = MFMA(ax[u], bw[u], acc0);
                }
            }
            if (t > 0) {
                _Float16* hb = h1s + ((t - 1) & 3) * (64 * 512) + arow * 512 + q * 8;
                half8 ah[16];
                #pragma unroll
                for (int u = 0; u < 16; ++u)
                    ah[u] = (M == 0) ? ldfrag_l3(hb + u * 32) : ldfrag_l2(hb + u * 32);
                #pragma unroll
                for (int u = 0; u < 16; ++u) {
                    if (u & 1) acc1 = MFMA(ah[u], bw[16 + u], acc1);
                    else       acc0 = MFMA(ah[u], bw[16 + u], acc0);
                }
            }
        }

        float hv[4];
        #pragma unroll
        for (int r = 0; r < 4; ++r)
            hv[r] = tanhf(acc0[r] + acc1[r] + bias);

        if (t == SEQ - 1) {
            #pragma unroll
            for (int r = 0; r < 4; ++r)
                out[(size_t)L * 64 * 512 + (size_t)(bg * 16 + q * 4 + r) * 512 + col]
                    = hv[r];
        }

        {
            _Float16* hw = ((L == 0) ? h0s : h1s) + (t & 3) * (64 * 512)
                         + (size_t)(bg * 16) * 512 + col;
            #pragma unroll
            for (int r = 0; r < 4; ++r) {
                union { _Float16 f; unsigned short u; } cv;
                cv.f = (_Float16)hv[r];
                if (M == 0) st2_l3(hw + (q * 4 + r) * 512, cv.u);
                else        st2_l2(hw + (q * 4 + r) * 512, cv.u);
            }
        }
        __atomic_signal_fence(__ATOMIC_SEQ_CST);
        __builtin_amdgcn_s_waitcnt(0);     // stores ACKed at L2 (fast) / MALL (slow)
        __atomic_signal_fence(__ATOMIC_SEQ_CST);
        if (lane == 0) {
            if (M == 0) stflag_l3(&flg[L * 32 + jg], t + 1);
            else        stflag_l2(&flg[L * 32 + jg], t + 1);
        }
    }
}

// ===== probe: steps 0..PROBE-1 on slow protocol, mirroring + validating fast =====
__device__ __forceinline__ void run_probe(
    const int lane, const int L, const int bg, const int jg,
    const int* __restrict__ src, const float* __restrict__ embed,
    const half8* bw, const float bias,
    _Float16* h0s, _Float16* h1s, int* flg,       // slow (truth)
    _Float16* f0s, _Float16* f1s, int* flgF,      // fast mirrors
    int* verdict)
{
    const int q    = lane >> 4;
    const int rr   = lane & 15;
    const int col  = jg * 16 + rr;
    const int arow = bg * 16 + rr;
    const int lf   = lane >> 5;
    int bad = 0;

    for (int t = 0; t < PROBE; ++t) {
        floatx4 acc0 = {0.f,0.f,0.f,0.f}, acc1 = {0.f,0.f,0.f,0.f};
        const int tgt = (L == 0) ? ((lf == 0) ? t : (t - 3))
                                 : ((lf == 0) ? (t + 1) : t);

        if (L == 0) {
            const int erow = src[arow * SEQ + t];
            const float* eb = embed + (size_t)erow * 512 + q * 8;
            half8 ax[16];
            #pragma unroll
            for (int u = 0; u < 16; ++u) ax[u] = cvt8(eb + u * 32);
            #pragma unroll
            for (int u = 0; u < 16; ++u) {
                if (u & 1) acc1 = MFMA(ax[u], bw[u], acc1);
                else       acc0 = MFMA(ax[u], bw[u], acc0);
            }
        }

        // slow poll (ground truth ordering)
        for (long it = 0; it < (1L << 26); ++it) {
            int v = ldflag_l3(&flg[lane]);
            if (__ballot(v >= tgt) == ~0ull) break;
            __builtin_amdgcn_s_sleep(1);
        }
        __atomic_signal_fence(__ATOMIC_SEQ_CST);

        // fast-flag visibility check (bounded; failure = defect, not hang)
        {
            bool ok = false;
            for (long it = 0; it < 256; ++it) {
                int v = ldflag_l2(&flgF[lane]);
                if (__ballot(v >= tgt) == ~0ull) { ok = true; break; }
                __builtin_amdgcn_s_sleep(1);
            }
            if (!ok) bad = 1;
        }

        if (L == 0) {
            if (t > 0) {
                const size_t off = ((t - 1) & 3) * (64 * 512) + arow * 512 + q * 8;
                half8 ah[16];
                #pragma unroll
                for (int u = 0; u < 16; ++u) {
                    ah[u] = ldfrag_l3(h0s + off + u * 32);
                    half8 fh = ldfrag_l2(f0s + off + u * 32);
                    bad |= neq8(ah[u], fh);
                }
                #pragma unroll
                for (int u = 0; u < 16; ++u) {
                    if (u & 1) acc1 = MFMA(ah[u], bw[16 + u], acc1);
                    else       acc0 = MFMA(ah[u], bw[16 + u], acc0);
                }
            }
        } else {
            {
                const size_t off = (t & 3) * (64 * 512) + arow * 512 + q * 8;
                half8 ax[16];
                #pragma unroll
                for (int u = 0; u < 16; ++u) {
                    ax[u] = ldfrag_l3(h0s + off + u * 32);
                    half8 fh = ldfrag_l2(f0s + off + u * 32);
                    bad |= neq8(ax[u], fh);
                }
                #pragma unroll
                for (int u = 0; u < 16; ++u) {
                    if (u & 1) acc1 = MFMA(ax[u], bw[u], acc1);
                    else       acc0 = MFMA(ax[u], bw[u], acc0);
                }
            }
            if (t > 0) {
                const size_t off = ((t - 1) & 3) * (64 * 512) + arow * 512 + q * 8;
                half8 ah[16];
                #pragma unroll
                for (int u = 0; u < 16; ++u) {
                    ah[u] = ldfrag_l3(h1s + off + u * 32);
                    half8 fh = ldfrag_l2(f1s + off + u * 32);
                    bad |= neq8(ah[u], fh);
                }
                #pragma unroll
                for (int u = 0; u < 16; ++u) {
                    if (u & 1) acc1 = MFMA(ah[u], bw[16 + u], acc1);
                    else       acc0 = MFMA(ah[u], bw[16 + u], acc0);
                }
            }
        }

        float hv[4];
        #pragma unroll
        for (int r = 0; r < 4; ++r)
            hv[r] = tanhf(acc0[r] + acc1[r] + bias);

        {
            const size_t off = (t & 3) * (64 * 512) + (size_t)(bg * 16) * 512 + col;
            _Float16* hwS = ((L == 0) ? h0s : h1s) + off;
            _Float16* hwF = ((L == 0) ? f0s : f1s) + off;
            #pragma unroll
            for (int r = 0; r < 4; ++r) {
                union { _Float16 f; unsigned short u; } cv;
                cv.f = (_Float16)hv[r];
                st2_l3(hwS + (q * 4 + r) * 512, cv.u);
                st2_l2(hwF + (q * 4 + r) * 512, cv.u);
            }
        }
        // fold wave verdict into group verdict before the last stamp
        if (t == PROBE - 1) {
            const int anybad = (__ballot(bad) != 0ull) ? 1 : 0;
            if (lane == 0 && anybad)
                __hip_atomic_fetch_or(verdict, 1, __ATOMIC_RELAXED,
                                      __HIP_MEMORY_SCOPE_AGENT);
        }
        __atomic_signal_fence(__ATOMIC_SEQ_CST);
        __builtin_amdgcn_s_waitcnt(0);   // h (both), verdict drained
        __atomic_signal_fence(__ATOMIC_SEQ_CST);
        if (lane == 0) {
            stflag_l2(&flgF[L * 32 + jg], t + 1);
            stflag_l3(&flg[L * 32 + jg], t + 1);
        }
    }
}

__global__ __launch_bounds__(128, 1)
void rnn_persist(const int* __restrict__ src, const float* __restrict__ embed,
                 const float* __restrict__ W_ih, const float* __restrict__ W_hh,
                 const float* __restrict__ b_ih, const float* __restrict__ b_hh,
                 float* __restrict__ out, _Float16* hS, _Float16* hF,
                 int* flagsS, int* flagsF, int* verdict)
{
    const int b = blockIdx.x;
    if ((b & 7) >= 4) return;            // residues 4..7: padding blocks, exit
    const int bg  = b & 7;               // 0..3; XCD = b % 8 under round-robin
    const int jg  = b >> 3;
    const int tid = threadIdx.x;
    const int lane = tid & 63;
    const int L    = tid >> 6;           // wave0 = layer 0, wave1 = layer 1

    // persistent weights: 16 cols x K=1024, f16, 128 VGPRs
    const int q = lane >> 4, rr = lane & 15;
    const int col = jg * 16 + rr;
    half8 bw[32];
    {
        const float* Wi = W_ih + ((size_t)L * 512 + col) * 512;
        const float* Wh = W_hh + ((size_t)L * 512 + col) * 512;
        #pragma unroll
        for (int u = 0; u < 16; ++u) bw[u]      = cvt8(Wi + u * 32 + q * 8);
        #pragma unroll
        for (int u = 0; u < 16; ++u) bw[16 + u] = cvt8(Wh + u * 32 + q * 8);
    }
    const float bias = b_ih[L * 512 + col] + b_hh[L * 512 + col];

    _Float16* h0sS = hS;  _Float16* h1sS = hS + 4 * 64 * 512;
    _Float16* h0sF = hF;  _Float16* h1sF = hF + 4 * 64 * 512;
    int* flgS = flagsS + bg * 64;
    int* flgF = flagsF + bg * 64;

    run_probe(lane, L, bg, jg, src, embed, bw, bias,
              h0sS, h1sS, flgS, h0sF, h1sF, flgF, &verdict[bg]);

    // group barrier: all 64 stamps >= PROBE  =>  all verdict ORs are at MALL
    for (long it = 0; it < (1L << 26); ++it) {
        int v = ldflag_l3(&flgS[lane]);
        if (__ballot(v >= PROBE) == ~0ull) break;
        __builtin_amdgcn_s_sleep(1);
    }
    __atomic_signal_fence(__ATOMIC_SEQ_CST);
    const int vd = __hip_atomic_load(&verdict[bg], __ATOMIC_RELAXED,
                                     __HIP_MEMORY_SCOPE_AGENT);

    if (vd == 0) {
        run_range<1>(PROBE, lane, L, bg, jg, src, embed, bw, bias, out,
                     h0sF, h1sF, flgF);
    } else {
        // telemetry stall ~2 ms: a slow verdict is readable from dur_us
        for (int i = 0; i < 600; ++i) __builtin_amdgcn_s_sleep(125);
        run_range<0>(PROBE, lane, L, bg, jg, src, embed, bw, bias, out,
                     h0sS, h1sS, flgS);
    }
}

extern "C" void kernel_launch(void* const* d_in, const int* in_sizes, int n_in,
                              void* d_out, int out_size, void* d_ws, size_t ws_size,
                              hipStream_t stream) {
    const int*   src   = (const int*)  d_in[0];
    const float* embed = (const float*)d_in[1];
    const float* W_ih  = (const float*)d_in[2];
    const float* W_hh  = (const float*)d_in[3];
    const float* b_ih  = (const float*)d_in[4];
    const float* b_hh  = (const float*)d_in[5];
    float* out = (float*)d_out;

    int*      flagsS  = (int*)d_ws;                  // bytes [0,1024)
    int*      flagsF  = (int*)d_ws + 256;            // bytes [1024,2048)
    int*      verdict = (int*)d_ws + 512;            // bytes [2048,2064)
    _Float16* hS = (_Float16*)((char*)d_ws + 16384);           // 512 KB slow h
    _Float16* hF = hS + 8 * 64 * 512;                          // 512 KB fast h

    // flags/verdict must start at 0 each launch (ws re-poisoned to 0xAA);
    // h slots need no init: t==0 skips all h-slot reads.
    hipMemsetAsync(d_ws, 0, 16384, stream);

    // 256 blocks x 128 threads; residues 0..3 (mod 8) active so each bg's 64
    // waves share one XCD. Co-residency by capacity: 256 blocks <= 256 CUs.
    rnn_persist<<<dim3(256), dim3(128), 0, stream>>>(
        src, embed, W_ih, W_hh, b_ih, b_hh, out, hS, hF, flagsS, flagsF, verdict);
}